// Round 5
// baseline (211.807 us; speedup 1.0000x reference)
//
#include <hip/hip_runtime.h>
#include <hip/hip_bf16.h>

#define NNODE 1024
#define DIM 128
#define HEADS 8
#define DK 16
#define EDIM 16
#define BN 8               // target nodes per attn block
#define NGRP 8             // m-group blocks per target row (128 rows each)
#define EF_ROW 20          // ef m-stride (dwords)
#define EFW_NSTR 104       // ef n-stride: banks 8*(np+sp) -> uniform 2-way = free (m136)
#define EFB 832            // one ef buffer (8 n * 104) dwords
#define WREG 1664          // per-wave region: 2 ping-pong ef buffers
#define LOG2E 1.44269504f

// smem: 4 wave-private ef regions (4*1664 = 6656 dw) overlaid by the final
// reduction scratch (8448 dw) -> arena = 8448 dw = 33792 B -> 4 blocks/CU by LDS.
#define SMEM_F 8448

// ---------------- Kernel 1: LayerNorm + QKV projection ----------------
__global__ __launch_bounds__(384)
void ln_qkv_kernel(const float* __restrict__ x,
                   const float* __restrict__ Wq, const float* __restrict__ bq,
                   const float* __restrict__ Wk, const float* __restrict__ bk,
                   const float* __restrict__ Wv, const float* __restrict__ bv,
                   const float* __restrict__ gamma, const float* __restrict__ beta,
                   float* __restrict__ qg, float* __restrict__ kg, float* __restrict__ vg) {
    const int n = blockIdx.x;
    const int t = threadIdx.x;
    __shared__ float hrow[DIM];
    __shared__ float part[4];

    float xv = 0.f;
    if (t < 128) {
        xv = x[n * DIM + t];
        float v = xv;
        #pragma unroll
        for (int off = 32; off >= 1; off >>= 1) v += __shfl_xor(v, off);
        if ((t & 63) == 0) part[t >> 6] = v;
    }
    __syncthreads();
    const float mu = (part[0] + part[1]) * (1.0f / DIM);
    const float dx = xv - mu;
    if (t < 128) {
        float v = dx * dx;
        #pragma unroll
        for (int off = 32; off >= 1; off >>= 1) v += __shfl_xor(v, off);
        if ((t & 63) == 0) part[2 + (t >> 6)] = v;
    }
    __syncthreads();
    if (t < 128) {
        const float var = (part[2] + part[3]) * (1.0f / DIM);
        hrow[t] = dx * rsqrtf(var + 1e-5f) * gamma[t] + beta[t];
    }
    __syncthreads();

    const int which = t >> 7;          // 0,1,2 -> q,k,v (wave-uniform)
    const int col = t & 127;
    const float* W = (which == 0) ? Wq : (which == 1) ? Wk : Wv;
    const float* b = (which == 0) ? bq : (which == 1) ? bk : bv;
    float* o       = (which == 0) ? qg : (which == 1) ? kg : vg;
    float a0 = b[col], a1 = 0.f;       // dual accumulators: break 128-deep dep chain
    #pragma unroll 8
    for (int i = 0; i < DIM; i += 2) {
        a0 = fmaf(hrow[i],     W[i * DIM + col],       a0);
        a1 = fmaf(hrow[i + 1], W[(i + 1) * DIM + col], a1);
    }
    o[n * DIM + col] = a0 + a1;
}

// ---------------- Kernel 2: wave-private attention, ef-only LDS ----------------
// grid = (1024/BN) * NGRP = 1024 blocks; 256 threads (4 waves), no hot-loop barriers.
// Round-4 lesson: k/v LDS round-trip was ~half the LDS-pipe load (38 wave-insts/chunk,
// ~24 us/CU of LDS pipe vs 16 us VALU) for data that is L2-resident (512 KB each)
// and only 4-lane-reused -> Common-mistake #7. This round: kk/vv and mask read
// DIRECTLY from global (L2); only ef stays in LDS (8x head-reuse), double-buffered
// per wave (issue-early / write-late, just 8 staged VGPRs -- affordable, unlike
// round 3's 24 which spilled).
// launch_bounds (256,1): empirical law rounds 1/3/4 -- 2nd arg N clamps VGPR at
// 256/N (N=2 -> 128 spilled round 3; N=4 -> 64 spilled round 1). N=1 -> cap 256,
// no spill; allocator lands ~140-170 -> 3 blocks/CU. Spill detector: WRITE_SIZE
// must stay exactly 8448 KB.
// Lane map (per wave): sp = lane>>5, np = (lane>>3)&3, h = lane&7;
// lane computes m = sp*2+j (j=0,1) x n = np+4*hf (hf=0,1).
// ALL register-array indices are compile-time constants.
__global__ __launch_bounds__(256, 1)
void attn_kernel(const float* __restrict__ qg, const float* __restrict__ kg,
                 const float* __restrict__ vg, const float* __restrict__ ef,
                 const int* __restrict__ mask,
                 const float* __restrict__ Wae, const float* __restrict__ bae,
                 float* __restrict__ acc) {
    const int t = threadIdx.x;
    const int lane = t & 63;
    const int wid = t >> 6;
    const int sp = lane >> 5;     // 0,1: m sub-pair selector
    const int np = (lane >> 3) & 3;
    const int h  = lane & 7;
    const int bx = blockIdx.x;
    const int n0  = (bx >> 3) * BN;
    const int grp = bx & 7;
    const int mb_w = grp * 128 + wid * 32;   // this wave's private 32 source rows

    __shared__ float smem[SMEM_F];
    float* ef_w = smem + wid * WREG;         // [2][8][EFW_NSTR] ping-pong

    // --- per-thread constants (global, L2-hot) ---
    float qreg[2][DK];
    #pragma unroll
    for (int hf = 0; hf < 2; ++hf) {
        const float* qp = qg + (size_t)(n0 + np + 4 * hf) * DIM + h * DK;
        #pragma unroll
        for (int d4 = 0; d4 < 4; ++d4) {
            const float4 qv = *(const float4*)(qp + d4 * 4);
            qreg[hf][d4 * 4 + 0] = qv.x; qreg[hf][d4 * 4 + 1] = qv.y;
            qreg[hf][d4 * 4 + 2] = qv.z; qreg[hf][d4 * 4 + 3] = qv.w;
        }
    }
    float waec[EDIM];
    #pragma unroll
    for (int e = 0; e < EDIM; ++e) waec[e] = Wae[e * HEADS + h] * LOG2E;
    const float baeh = bae[h] * LOG2E;

    float sl[2] = {0.f, 0.f};
    float accv[2][DK], accT[2][EDIM];
    #pragma unroll
    for (int hf = 0; hf < 2; ++hf) {
        #pragma unroll
        for (int d = 0; d < DK; ++d) accv[hf][d] = 0.f;
        #pragma unroll
        for (int e = 0; e < EDIM; ++e) accT[hf][e] = 0.f;
    }

    // --- prologue: stage ef chunk 0 into buffer 0 (wave-private, no barrier) ---
    #pragma unroll
    for (int r = 0; r < 2; ++r) {
        const int idx = r * 64 + lane;       // 0..127 float4-chunks of [4m][8n][16e]
        const int nn = idx >> 4, mm = (idx >> 2) & 3, q4 = idx & 3;
        const float4 ev0 = *(const float4*)(ef + ((size_t)(n0 + nn) * NNODE + mb_w + mm) * EDIM + q4 * 4);
        *(float4*)&ef_w[nn * EFW_NSTR + mm * EF_ROW + q4 * 4] = ev0;
    }

    #pragma unroll 1
    for (int c = 0; c < 8; ++c) {
        const int mb = mb_w + c * 4;         // 4 m-rows this chunk
        const float* efc = ef_w + (c & 1) * EFB;
        const bool pf = (c < 7);

        // --- issue-early: ef global loads for chunk c+1 (8 staged VGPRs) ---
        float4 ev[2];
        if (pf) {
            #pragma unroll
            for (int r = 0; r < 2; ++r) {
                const int idx = r * 64 + lane;
                const int nn = idx >> 4, mm = (idx >> 2) & 3, q4 = idx & 3;
                ev[r] = *(const float4*)(ef + ((size_t)(n0 + nn) * NNODE + (mb + 4) + mm) * EDIM + q4 * 4);
            }
        }

        // --- mask direct from L2: int2 covers both j for this (hf, chunk) ---
        int2 mk[2];
        #pragma unroll
        for (int hf = 0; hf < 2; ++hf)
            mk[hf] = *(const int2*)(mask + (size_t)(n0 + np + 4 * hf) * NNODE + mb + 2 * sp);

        // --- compute: 2 m per lane; kk/vv straight from global (L2-resident) ---
        #pragma unroll
        for (int j = 0; j < 2; ++j) {
            const int ml = sp * 2 + j;
            float kk[DK], vv[DK];
            const float* kp = kg + (size_t)(mb + ml) * DIM + h * DK;
            const float* vp = vg + (size_t)(mb + ml) * DIM + h * DK;
            #pragma unroll
            for (int d4 = 0; d4 < 4; ++d4) {
                const float4 k4 = *(const float4*)(kp + d4 * 4);
                kk[d4 * 4 + 0] = k4.x; kk[d4 * 4 + 1] = k4.y;
                kk[d4 * 4 + 2] = k4.z; kk[d4 * 4 + 3] = k4.w;
                const float4 v4 = *(const float4*)(vp + d4 * 4);
                vv[d4 * 4 + 0] = v4.x; vv[d4 * 4 + 1] = v4.y;
                vv[d4 * 4 + 2] = v4.z; vv[d4 * 4 + 3] = v4.w;
            }
            #pragma unroll
            for (int hf = 0; hf < 2; ++hf) {
                const int n = np + 4 * hf;
                const float* ep = &efc[n * EFW_NSTR + ml * EF_ROW];
                float efv[EDIM];
                #pragma unroll
                for (int e4 = 0; e4 < 4; ++e4) {     // STATIC e4 (stride algebra: 2-way max)
                    const float4 e4v = *(const float4*)(ep + e4 * 4);
                    efv[e4 * 4 + 0] = e4v.x; efv[e4 * 4 + 1] = e4v.y;
                    efv[e4 * 4 + 2] = e4v.z; efv[e4 * 4 + 3] = e4v.w;
                }
                float bias = baeh, dot = 0.f;
                #pragma unroll
                for (int e = 0; e < EDIM; ++e) bias = fmaf(efv[e], waec[e], bias);
                #pragma unroll
                for (int d = 0; d < DK; ++d) dot = fmaf(qreg[hf][d], kk[d], dot);
                const float lg = fmaf(dot, 0.25f * LOG2E, bias);
                const int mv = j ? mk[hf].y : mk[hf].x;   // j static in unrolled loop
                const float p = mv ? __builtin_amdgcn_exp2f(lg) : 0.f;
                sl[hf] += p;
                #pragma unroll
                for (int d = 0; d < DK; ++d) accv[hf][d] = fmaf(p, vv[d], accv[hf][d]);
                #pragma unroll
                for (int e = 0; e < EDIM; ++e) accT[hf][e] = fmaf(p, efv[e], accT[hf][e]);
            }
        }

        // --- write-late: staged ef regs -> other buffer (wave-private, no barrier) ---
        if (pf) {
            float* efn = ef_w + ((c + 1) & 1) * EFB;
            #pragma unroll
            for (int r = 0; r < 2; ++r) {
                const int idx = r * 64 + lane;
                const int nn = idx >> 4, mm = (idx >> 2) & 3, q4 = idx & 3;
                *(float4*)&efn[nn * EFW_NSTR + mm * EF_ROW + q4 * 4] = ev[r];
            }
        }
    }

    // --- reduce sp-pairs within wave (lane ^ 32): combines the two m-subsets ---
    #pragma unroll
    for (int hf = 0; hf < 2; ++hf) {
        sl[hf] += __shfl_xor(sl[hf], 32);
        #pragma unroll
        for (int d = 0; d < DK; ++d) accv[hf][d] += __shfl_xor(accv[hf][d], 32);
        #pragma unroll
        for (int e = 0; e < EDIM; ++e) accT[hf][e] += __shfl_xor(accT[hf][e], 32);
    }
    __syncthreads();                 // all waves done with private regions -> overlay
    float* red = smem;               // [w4][np4][h8][hf2][33] = 8448 f32 overlay
    if (lane < 32) {
        float* rp = &red[((wid * 4 + np) * 8 + h) * 66];
        #pragma unroll
        for (int hf = 0; hf < 2; ++hf) {
            rp[hf * 33 + 0] = sl[hf];
            #pragma unroll
            for (int d = 0; d < DK; ++d) rp[hf * 33 + 1 + d] = accv[hf][d];
            #pragma unroll
            for (int e = 0; e < EDIM; ++e) rp[hf * 33 + 17 + e] = accT[hf][e];
        }
    }
    __syncthreads();
    // --- combine 4 wave copies, plain store to this block's group slot ---
    // acc layout: [n][grp][264]; each (n,grp) written by exactly one block.
    for (int v = t; v < BN * HEADS * 33; v += 256) {   // 2112 values
        const int n = v / 264;
        const int rem = v - n * 264;
        const int hh = rem / 33;
        const int idx = rem - hh * 33;
        const int nnp = n & 3, hf = n >> 2;
        float sum = 0.f;
        #pragma unroll
        for (int w = 0; w < 4; ++w)
            sum += red[((w * 4 + nnp) * 8 + hh) * 66 + hf * 33 + idx];
        acc[((size_t)(n0 + n) * NGRP + grp) * 264 + rem] = sum;
    }
}

// ---------------- Kernel 3: epilogue (sum groups, Wve, normalize, Wo, residual) ----------------
__global__ __launch_bounds__(128)
void final_kernel(const float* __restrict__ acc,
                  const float* __restrict__ Wve, const float* __restrict__ bve,
                  const float* __restrict__ x,
                  const float* __restrict__ Wo, const float* __restrict__ bo,
                  float* __restrict__ out) {
    const int n = blockIdx.x, t = threadIdx.x;
    __shared__ float ab[HEADS * 33];
    __shared__ float orow[DIM];
    const float* ap = acc + (size_t)n * NGRP * 264;
    for (int u = t; u < HEADS * 33; u += 128) {
        float sv = 0.f;
        #pragma unroll
        for (int g = 0; g < NGRP; ++g) sv += ap[g * 264 + u];
        ab[u] = sv;
    }
    __syncthreads();
    const int col = t, hh = col >> 4, dd = col & 15;
    const float slv = ab[hh * 33];
    float acc2 = 0.f;
    #pragma unroll
    for (int e = 0; e < EDIM; ++e) acc2 = fmaf(ab[hh * 33 + 17 + e], Wve[e * DIM + col], acc2);
    orow[col] = (ab[hh * 33 + 1 + dd] + acc2) / slv + bve[col];
    __syncthreads();
    float o0 = bo[col] + x[(size_t)n * DIM + col], o1 = 0.f;
    #pragma unroll 8
    for (int i = 0; i < DIM; i += 2) {
        o0 = fmaf(orow[i],     Wo[i * DIM + col],       o0);
        o1 = fmaf(orow[i + 1], Wo[(i + 1) * DIM + col], o1);
    }
    out[(size_t)n * DIM + col] = o0 + o1;
}

extern "C" void kernel_launch(void* const* d_in, const int* in_sizes, int n_in,
                              void* d_out, int out_size, void* d_ws, size_t ws_size,
                              hipStream_t stream) {
    const float* x     = (const float*)d_in[0];
    const float* ef    = (const float*)d_in[1];
    const int*   mask  = (const int*)d_in[2];
    const float* Wq    = (const float*)d_in[3];
    const float* bq    = (const float*)d_in[4];
    const float* Wk    = (const float*)d_in[5];
    const float* bk    = (const float*)d_in[6];
    const float* Wv    = (const float*)d_in[7];
    const float* bv    = (const float*)d_in[8];
    const float* Wae   = (const float*)d_in[9];
    const float* bae   = (const float*)d_in[10];
    const float* Wve   = (const float*)d_in[11];
    const float* bve   = (const float*)d_in[12];
    const float* Wo    = (const float*)d_in[13];
    const float* bo    = (const float*)d_in[14];
    const float* gamma = (const float*)d_in[15];
    const float* beta  = (const float*)d_in[16];

    float* ws = (float*)d_ws;
    float* accb = ws;                                   // 1024*8*264 f32
    float* qg   = ws + (size_t)NNODE * NGRP * 264;
    float* kg   = qg + (size_t)NNODE * DIM;
    float* vg   = kg + (size_t)NNODE * DIM;

    ln_qkv_kernel<<<NNODE, 384, 0, stream>>>(x, Wq, bq, Wk, bk, Wv, bv, gamma, beta, qg, kg, vg);
    attn_kernel<<<(NNODE / BN) * NGRP, 256, 0, stream>>>(qg, kg, vg, ef, mask, Wae, bae, accb);
    final_kernel<<<NNODE, 128, 0, stream>>>(accb, Wve, bve, x, Wo, bo, (float*)d_out);
}

// Round 7
// 183.918 us; speedup vs baseline: 1.1516x; 1.1516x over previous
//
#include <hip/hip_runtime.h>
#include <hip/hip_bf16.h>

#define NNODE 1024
#define DIM 128
#define HEADS 8
#define DK 16
#define EDIM 16
#define BN 8               // target nodes per attn block
#define NGRP 8             // m-group blocks per target row (128 rows each)
#define LOG2E 1.44269504f

// per-WAVE region (dwords), double-buffered, UNPADDED (global_load_lds writes
// linearly; conflict-freedom comes from the source/read sub-slot rotation):
//   buf parity p at wid*WREG + p*PAR:
//     k  [4 rows][128]   at +0      (dword = row*128 + h*16 + slot*4, slot=(d4+(h>>1))&3)
//     v  [4 rows][128]   at +512    (same swizzle)
//     ef [8 n][4 m][16]  at +1024   (dword = nn*64 + ml*16 + slot*4, slot=(e4+nn)&3)
#define PAR 1536
#define WREG (2 * PAR)
#define SMEM_F (4 * WREG)  // 12288 dw = 49152 B; reduction overlay (8448 dw) fits

// ---------------- Kernel 1: LayerNorm + QKV projection ----------------
__global__ __launch_bounds__(384)
void ln_qkv_kernel(const float* __restrict__ x,
                   const float* __restrict__ Wq, const float* __restrict__ bq,
                   const float* __restrict__ Wk, const float* __restrict__ bk,
                   const float* __restrict__ Wv, const float* __restrict__ bv,
                   const float* __restrict__ gamma, const float* __restrict__ beta,
                   float* __restrict__ qg, float* __restrict__ kg, float* __restrict__ vg) {
    const int n = blockIdx.x;
    const int t = threadIdx.x;
    __shared__ float hrow[DIM];
    __shared__ float part[4];

    float xv = 0.f;
    if (t < 128) {
        xv = x[n * DIM + t];
        float v = xv;
        #pragma unroll
        for (int off = 32; off >= 1; off >>= 1) v += __shfl_xor(v, off);
        if ((t & 63) == 0) part[t >> 6] = v;
    }
    __syncthreads();
    const float mu = (part[0] + part[1]) * (1.0f / DIM);
    const float dx = xv - mu;
    if (t < 128) {
        float v = dx * dx;
        #pragma unroll
        for (int off = 32; off >= 1; off >>= 1) v += __shfl_xor(v, off);
        if ((t & 63) == 0) part[2 + (t >> 6)] = v;
    }
    __syncthreads();
    if (t < 128) {
        const float var = (part[2] + part[3]) * (1.0f / DIM);
        hrow[t] = dx * rsqrtf(var + 1e-5f) * gamma[t] + beta[t];
    }
    __syncthreads();

    const int which = t >> 7;          // 0,1,2 -> q,k,v (wave-uniform)
    const int col = t & 127;
    const float* W = (which == 0) ? Wq : (which == 1) ? Wk : Wv;
    const float* b = (which == 0) ? bq : (which == 1) ? bk : bv;
    float* o       = (which == 0) ? qg : (which == 1) ? kg : vg;
    float a0 = b[col], a1 = 0.f;       // dual accumulators: break 128-deep dep chain
    #pragma unroll 8
    for (int i = 0; i < DIM; i += 2) {
        a0 = fmaf(hrow[i],     W[i * DIM + col],       a0);
        a1 = fmaf(hrow[i + 1], W[(i + 1) * DIM + col], a1);
    }
    o[n * DIM + col] = a0 + a1;
}

// async 16B global->LDS DMA (no VGPR roundtrip, no ds_write)
__device__ __forceinline__ void gll16(const float* g, float* l) {
    auto* gp = (const __attribute__((address_space(1))) unsigned int*)(g);
    auto* lp = (__attribute__((address_space(3))) unsigned int*)(l);
    __builtin_amdgcn_global_load_lds(gp, lp, 16, 0, 0);
}

// ---------------- Kernel 2: wave-private attention, DMA-staged, counted vmcnt ----------------
// grid = (1024/BN)*NGRP = 1024 blocks; 256 threads (4 waves), no hot-loop barriers.
// Round-5 lesson: k/v from global = serial L2 latency per chunk (91 us). Round-4
// floor analysis: ~20.5 us/CU of LDS-read pipe is the hard floor; the rest of the
// 54 us was exposed staging latency (stage and compute of the SAME chunk
// back-to-back). This round: global_load_lds DMA into wave-private double
// buffers; batch for chunk c+1 (6 DMA + 2 mask loads = 8 VMEM) is issued BEFORE
// computing chunk c; s_waitcnt vmcnt(8) (never 0 in steady state) drains only
// chunk c's batch -> full chunk compute (~1100 cyc) covers the load latency.
// No staging VGPRs -> the round-1/3 spill trap is structurally impossible.
// Round-6 hardening: explicit vmcnt(0) after the constant-load prologue makes
// the in-loop ledger exact (otherwise leftover const loads made vmcnt(8)
// conservative-but-correct under FIFO-oldest draining, m135).
// LDS unpadded (DMA writes linearly); bank conflicts killed by rotating the 16B
// sub-slot in BOTH the global source addr and the read addr (rule #21):
//   k/v: slot = (d4 + (h>>1)) & 3 -> per-inst banks tile all 32, 2-way max.
//   ef:  slot = (e4 + nn)  & 3 -> per-inst 2-way max (h 8-way same-addr bcast).
// Registers stay naturally indexed (rotation lives in addresses only, rule #20).
// Mask prefetched a chunk ahead into parity-named regs (2x-unrolled bodies).
__global__ __launch_bounds__(256, 1)
void attn_kernel(const float* __restrict__ qg, const float* __restrict__ kg,
                 const float* __restrict__ vg, const float* __restrict__ ef,
                 const int* __restrict__ mask,
                 const float* __restrict__ Wae, const float* __restrict__ bae,
                 float* __restrict__ acc) {
    const int t = threadIdx.x;
    const int lane = t & 63;
    const int wid = t >> 6;
    const int sp = lane >> 5;     // 0,1: m sub-pair selector
    const int np = (lane >> 3) & 3;
    const int h  = lane & 7;
    const int bx = blockIdx.x;
    const int n0  = (bx >> 3) * BN;
    const int grp = bx & 7;
    const int mb_w = grp * 128 + wid * 32;   // this wave's private 32 source rows

    __shared__ float smem[SMEM_F];
    float* wreg = smem + wid * WREG;         // wave-uniform base

    // --- per-thread constants (global, L2-hot) ---
    float qreg[2][DK];
    #pragma unroll
    for (int hf = 0; hf < 2; ++hf) {
        const float* qp = qg + (size_t)(n0 + np + 4 * hf) * DIM + h * DK;
        #pragma unroll
        for (int d4 = 0; d4 < 4; ++d4) {
            const float4 qv = *(const float4*)(qp + d4 * 4);
            qreg[hf][d4 * 4 + 0] = qv.x; qreg[hf][d4 * 4 + 1] = qv.y;
            qreg[hf][d4 * 4 + 2] = qv.z; qreg[hf][d4 * 4 + 3] = qv.w;
        }
    }
    float waec[EDIM];
    #pragma unroll
    for (int e = 0; e < EDIM; ++e) waec[e] = Wae[e * HEADS + h] * LOG2E;
    const float baeh = bae[h] * LOG2E;

    float sl[2] = {0.f, 0.f};
    float accv[2][DK], accT[2][EDIM];
    #pragma unroll
    for (int hf = 0; hf < 2; ++hf) {
        #pragma unroll
        for (int d = 0; d < DK; ++d) accv[hf][d] = 0.f;
        #pragma unroll
        for (int e = 0; e < EDIM; ++e) accT[hf][e] = 0.f;
    }

    // --- DMA source pointers (lane-swizzled so linear LDS dst = swizzled layout) ---
    const int s0   = lane & 3;
    const int h0   = (lane >> 2) & 7;
    const int row0 = lane >> 5;                       // k/v: rows 0..1 (inst 0), +2 (inst 1)
    const int koff = row0 * 128 + h0 * 16 + (((s0 - (h0 >> 1)) & 3) << 2);
    const float* ks0 = kg + (size_t)mb_w * 128 + koff;
    const float* ks1 = ks0 + 256;
    const float* vs0 = vg + (size_t)mb_w * 128 + koff;
    const float* vs1 = vs0 + 256;
    const int nn0 = lane >> 4;                        // ef: nn 0..3 (inst 0), +4 (inst 1)
    const int ml0 = (lane >> 2) & 3;
    const float* es0 = ef + ((size_t)(n0 + nn0) * NNODE + mb_w + ml0) * EDIM
                          + (((s0 - nn0) & 3) << 2);
    const float* es1 = es0 + (size_t)4 * NNODE * EDIM;
    const int* mp0 = mask + (size_t)(n0 + np) * NNODE + mb_w + 2 * sp;
    const int* mp1 = mp0 + (size_t)4 * NNODE;

    // --- read-side rotated sub-slot offsets (static-indexed reg arrays) ---
    int krot[4], erot[4];
    const int rotk = (h >> 1) & 3;
    #pragma unroll
    for (int i = 0; i < 4; ++i) {
        krot[i] = ((i + rotk) & 3) << 2;
        erot[i] = ((i + np) & 3) << 2;
    }

    // ledger hardening: drain ALL prologue const loads so in-loop counts are exact
    asm volatile("s_waitcnt vmcnt(0)" ::: "memory");

    int2 mkA[2], mkB[2];

#define ISSUE_BATCH(P, MKN)                                              \
    do {                                                                 \
        float* db = wreg + (P);                                          \
        gll16(ks0, db);        gll16(ks1, db + 256);                     \
        gll16(vs0, db + 512);  gll16(vs1, db + 768);                     \
        gll16(es0, db + 1024); gll16(es1, db + 1280);                    \
        MKN[0] = *(const int2*)mp0; MKN[1] = *(const int2*)mp1;          \
        ks0 += 512; ks1 += 512; vs0 += 512; vs1 += 512;                  \
        es0 += 64;  es1 += 64;  mp0 += 4;   mp1 += 4;                    \
    } while (0)

#define COMPUTE_CHUNK(P, MK)                                                   \
    do {                                                                       \
        const float* kl = wreg + (P) + sp * 256 + h * 16;                      \
        const float* vl = kl + 512;                                            \
        const float* el = wreg + (P) + 1024 + np * 64 + sp * 32;               \
        _Pragma("unroll")                                                      \
        for (int j = 0; j < 2; ++j) {                                          \
            float kk[DK], vv[DK];                                              \
            _Pragma("unroll")                                                  \
            for (int i = 0; i < 4; ++i) {                                      \
                const float4 k4 = *(const float4*)(kl + j * 128 + krot[i]);    \
                kk[i*4+0]=k4.x; kk[i*4+1]=k4.y; kk[i*4+2]=k4.z; kk[i*4+3]=k4.w;\
                const float4 v4 = *(const float4*)(vl + j * 128 + krot[i]);    \
                vv[i*4+0]=v4.x; vv[i*4+1]=v4.y; vv[i*4+2]=v4.z; vv[i*4+3]=v4.w;\
            }                                                                  \
            _Pragma("unroll")                                                  \
            for (int hf = 0; hf < 2; ++hf) {                                   \
                float efv[EDIM];                                               \
                _Pragma("unroll")                                              \
                for (int i = 0; i < 4; ++i) {                                  \
                    const float4 e4 =                                          \
                        *(const float4*)(el + hf * 256 + j * 16 + erot[i]);    \
                    efv[i*4+0]=e4.x; efv[i*4+1]=e4.y;                          \
                    efv[i*4+2]=e4.z; efv[i*4+3]=e4.w;                          \
                }                                                              \
                float bias = baeh, dot = 0.f;                                  \
                _Pragma("unroll")                                              \
                for (int e = 0; e < EDIM; ++e) bias = fmaf(efv[e], waec[e], bias); \
                _Pragma("unroll")                                              \
                for (int d = 0; d < DK; ++d) dot = fmaf(qreg[hf][d], kk[d], dot);  \
                const float lg = fmaf(dot, 0.25f * LOG2E, bias);               \
                const int mv = j ? MK[hf].y : MK[hf].x;                        \
                const float p = mv ? __builtin_amdgcn_exp2f(lg) : 0.f;         \
                sl[hf] += p;                                                   \
                _Pragma("unroll")                                              \
                for (int d = 0; d < DK; ++d) accv[hf][d] = fmaf(p, vv[d], accv[hf][d]); \
                _Pragma("unroll")                                              \
                for (int e = 0; e < EDIM; ++e) accT[hf][e] = fmaf(p, efv[e], accT[hf][e]); \
            }                                                                  \
        }                                                                      \
    } while (0)

    // prologue: batch for chunk 0 (8 outstanding)
    ISSUE_BATCH(0, mkA);

    // main loop, 2x unrolled for parity-named buffers/mask regs.
    // Ledger (exact after prologue drain): top of even body: 8 outstanding
    // (chunk cc). Issue 8 (cc+1) -> 16; vmcnt(8) drains chunk cc's batch;
    // compute. Odd body symmetric; last odd body (cc==6 -> chunk 7) issues
    // nothing and drains to 0.
    #pragma unroll 1
    for (int cc = 0; cc < 8; cc += 2) {
        ISSUE_BATCH(PAR, mkB);
        asm volatile("s_waitcnt vmcnt(8)" ::: "memory");
        COMPUTE_CHUNK(0, mkA);
        if (cc < 6) {
            ISSUE_BATCH(0, mkA);
            asm volatile("s_waitcnt vmcnt(8)" ::: "memory");
        } else {
            asm volatile("s_waitcnt vmcnt(0)" ::: "memory");
        }
        COMPUTE_CHUNK(PAR, mkB);
    }
#undef ISSUE_BATCH
#undef COMPUTE_CHUNK

    // --- reduce sp-pairs within wave (lane ^ 32): combines the two m-subsets ---
    #pragma unroll
    for (int hf = 0; hf < 2; ++hf) {
        sl[hf] += __shfl_xor(sl[hf], 32);
        #pragma unroll
        for (int d = 0; d < DK; ++d) accv[hf][d] += __shfl_xor(accv[hf][d], 32);
        #pragma unroll
        for (int e = 0; e < EDIM; ++e) accT[hf][e] += __shfl_xor(accT[hf][e], 32);
    }
    __syncthreads();                 // all waves done with private regions -> overlay
    float* red = smem;               // [w4][np4][h8][hf2][33] = 8448 f32 overlay
    if (lane < 32) {
        float* rp = &red[((wid * 4 + np) * 8 + h) * 66];
        #pragma unroll
        for (int hf = 0; hf < 2; ++hf) {
            rp[hf * 33 + 0] = sl[hf];
            #pragma unroll
            for (int d = 0; d < DK; ++d) rp[hf * 33 + 1 + d] = accv[hf][d];
            #pragma unroll
            for (int e = 0; e < EDIM; ++e) rp[hf * 33 + 17 + e] = accT[hf][e];
        }
    }
    __syncthreads();
    // --- combine 4 wave copies, plain store to this block's group slot ---
    for (int v = t; v < BN * HEADS * 33; v += 256) {   // 2112 values
        const int n = v / 264;
        const int rem = v - n * 264;
        const int hh = rem / 33;
        const int idx = rem - hh * 33;
        const int nnp = n & 3, hf = n >> 2;
        float sum = 0.f;
        #pragma unroll
        for (int w = 0; w < 4; ++w)
            sum += red[((w * 4 + nnp) * 8 + hh) * 66 + hf * 33 + idx];
        acc[((size_t)(n0 + n) * NGRP + grp) * 264 + rem] = sum;
    }
}

// ---------------- Kernel 3: epilogue (sum groups, Wve, normalize, Wo, residual) ----------------
__global__ __launch_bounds__(128)
void final_kernel(const float* __restrict__ acc,
                  const float* __restrict__ Wve, const float* __restrict__ bve,
                  const float* __restrict__ x,
                  const float* __restrict__ Wo, const float* __restrict__ bo,
                  float* __restrict__ out) {
    const int n = blockIdx.x, t = threadIdx.x;
    __shared__ float ab[HEADS * 33];
    __shared__ float orow[DIM];
    const float* ap = acc + (size_t)n * NGRP * 264;
    for (int u = t; u < HEADS * 33; u += 128) {
        float sv = 0.f;
        #pragma unroll
        for (int g = 0; g < NGRP; ++g) sv += ap[g * 264 + u];
        ab[u] = sv;
    }
    __syncthreads();
    const int col = t, hh = col >> 4, dd = col & 15;
    const float slv = ab[hh * 33];
    float acc2 = 0.f;
    #pragma unroll
    for (int e = 0; e < EDIM; ++e) acc2 = fmaf(ab[hh * 33 + 17 + e], Wve[e * DIM + col], acc2);
    orow[col] = (ab[hh * 33 + 1 + dd] + acc2) / slv + bve[col];
    __syncthreads();
    float o0 = bo[col] + x[(size_t)n * DIM + col], o1 = 0.f;
    #pragma unroll 8
    for (int i = 0; i < DIM; i += 2) {
        o0 = fmaf(orow[i],     Wo[i * DIM + col],       o0);
        o1 = fmaf(orow[i + 1], Wo[(i + 1) * DIM + col], o1);
    }
    out[(size_t)n * DIM + col] = o0 + o1;
}

extern "C" void kernel_launch(void* const* d_in, const int* in_sizes, int n_in,
                              void* d_out, int out_size, void* d_ws, size_t ws_size,
                              hipStream_t stream) {
    const float* x     = (const float*)d_in[0];
    const float* ef    = (const float*)d_in[1];
    const int*   mask  = (const int*)d_in[2];
    const float* Wq    = (const float*)d_in[3];
    const float* bq    = (const float*)d_in[4];
    const float* Wk    = (const float*)d_in[5];
    const float* bk    = (const float*)d_in[6];
    const float* Wv    = (const float*)d_in[7];
    const float* bv    = (const float*)d_in[8];
    const float* Wae   = (const float*)d_in[9];
    const float* bae   = (const float*)d_in[10];
    const float* Wve   = (const float*)d_in[11];
    const float* bve   = (const float*)d_in[12];
    const float* Wo    = (const float*)d_in[13];
    const float* bo    = (const float*)d_in[14];
    const float* gamma = (const float*)d_in[15];
    const float* beta  = (const float*)d_in[16];

    float* ws = (float*)d_ws;
    float* accb = ws;                                   // 1024*8*264 f32
    float* qg   = ws + (size_t)NNODE * NGRP * 264;
    float* kg   = qg + (size_t)NNODE * DIM;
    float* vg   = kg + (size_t)NNODE * DIM;

    ln_qkv_kernel<<<NNODE, 384, 0, stream>>>(x, Wq, bq, Wk, bk, Wv, bv, gamma, beta, qg, kg, vg);
    attn_kernel<<<(NNODE / BN) * NGRP, 256, 0, stream>>>(qg, kg, vg, ef, mask, Wae, bae, accb);
    final_kernel<<<NNODE, 128, 0, stream>>>(accb, Wve, bve, x, Wo, bo, (float*)d_out);
}

// Round 8
// 171.412 us; speedup vs baseline: 1.2357x; 1.0730x over previous
//
#include <hip/hip_runtime.h>
#include <hip/hip_bf16.h>

#define NNODE 1024
#define DIM 128
#define HEADS 8
#define DK 16
#define EDIM 16
#define BN 8               // target nodes per attn block
#define NGRP 8             // m-group blocks per target row (128 rows each)
#define LOG2E 1.44269504f

// per-WAVE region (dwords), double-buffered, UNPADDED (global_load_lds writes
// linearly; conflict-freedom via source-swizzle + rotated read, verified r7:
// bank conflicts 1.83M -> 254K):
//   parity p at wid*WREG + p*PAR:
//     k  [2 rows][128]  at +0    (LDS slot s holds global d-slot (s-(h>>1))&3)
//     v  [2 rows][128]  at +256
//     ef [8 n][2 m][16] at +512  (LDS slot s holds global e-slot (s-nn)&3)
#define PAR 768
#define WREG (2 * PAR)
#define SMEM_F 8448        // overlay (reduction scratch) dominates: 33792 B -> 4 blocks/CU

// ---------------- Kernel 1: LayerNorm + QKV projection + mask bit-pack ----------------
__global__ __launch_bounds__(384)
void ln_qkv_kernel(const float* __restrict__ x,
                   const float* __restrict__ Wq, const float* __restrict__ bq,
                   const float* __restrict__ Wk, const float* __restrict__ bk,
                   const float* __restrict__ Wv, const float* __restrict__ bv,
                   const float* __restrict__ gamma, const float* __restrict__ beta,
                   const int* __restrict__ mask,
                   float* __restrict__ qg, float* __restrict__ kg, float* __restrict__ vg,
                   unsigned char* __restrict__ maskb) {
    const int n = blockIdx.x;
    const int t = threadIdx.x;
    __shared__ float hrow[DIM];
    __shared__ float part[4];

    // --- mask bit-pack: row n -> 128 bytes (bit i of byte t = mask[n][t*8+i]) ---
    if (t < 128) {
        const int* mrow = mask + (size_t)n * NNODE + t * 8;
        unsigned pb = 0;
        #pragma unroll
        for (int i = 0; i < 8; ++i) pb |= (mrow[i] ? 1u : 0u) << i;
        maskb[(size_t)n * 128 + t] = (unsigned char)pb;
    }

    float xv = 0.f;
    if (t < 128) {
        xv = x[n * DIM + t];
        float v = xv;
        #pragma unroll
        for (int off = 32; off >= 1; off >>= 1) v += __shfl_xor(v, off);
        if ((t & 63) == 0) part[t >> 6] = v;
    }
    __syncthreads();
    const float mu = (part[0] + part[1]) * (1.0f / DIM);
    const float dx = xv - mu;
    if (t < 128) {
        float v = dx * dx;
        #pragma unroll
        for (int off = 32; off >= 1; off >>= 1) v += __shfl_xor(v, off);
        if ((t & 63) == 0) part[2 + (t >> 6)] = v;
    }
    __syncthreads();
    if (t < 128) {
        const float var = (part[2] + part[3]) * (1.0f / DIM);
        hrow[t] = dx * rsqrtf(var + 1e-5f) * gamma[t] + beta[t];
    }
    __syncthreads();

    const int which = t >> 7;          // 0,1,2 -> q,k,v (wave-uniform)
    const int col = t & 127;
    const float* W = (which == 0) ? Wq : (which == 1) ? Wk : Wv;
    const float* b = (which == 0) ? bq : (which == 1) ? bk : bv;
    float* o       = (which == 0) ? qg : (which == 1) ? kg : vg;
    float a0 = b[col], a1 = 0.f;       // dual accumulators: break 128-deep dep chain
    #pragma unroll 8
    for (int i = 0; i < DIM; i += 2) {
        a0 = fmaf(hrow[i],     W[i * DIM + col],       a0);
        a1 = fmaf(hrow[i + 1], W[(i + 1) * DIM + col], a1);
    }
    o[n * DIM + col] = a0 + a1;
}

// async 16B global->LDS DMA (no VGPR roundtrip, no ds_write)
__device__ __forceinline__ void gll16(const float* g, float* l) {
    auto* gp = (const __attribute__((address_space(1))) unsigned int*)(g);
    auto* lp = (__attribute__((address_space(3))) unsigned int*)(l);
    __builtin_amdgcn_global_load_lds(gp, lp, 16, 0, 0);
}

// ---------------- Kernel 2: wave-private attention, DMA-staged, 4-blocks/CU ----------------
// grid = 1024 blocks x 256 threads (4 waves), no hot-loop barriers.
// Round-7 lesson: pipeline worked (conflicts 254K, per-block ~25% faster) but
// VGPR 156 + LDS 48K -> 3 blocks/CU resident of 4/CU work = straggler round.
// This round keeps the r7 pipeline but squeezes into the r4 envelope:
//   chunk = 2 m-rows (16 chunks), PAR=768 -> LDS arena = overlay = 33792 B (4 blk/CU);
//   batch = 3 DMA (k,v,ef one inst each); vmcnt(3) steady, vmcnt(0) only at tail;
//   mask = bit-packed u32 x2 held in registers the whole kernel (bit (2c+sp));
//   no mask prefetch regs/pointers, no second per-operand pointers (r7: -18 VGPR);
//   launch_bounds (256,2): clamp 128 = 4 waves/SIMD; r4 proved 115-persistent +
//   this loop body fits. Spill detector: WRITE_SIZE must stay ~8448 KB.
// Lane map: sp = lane>>5 (m parity), np = (lane>>3)&3, h = lane&7;
// lane computes m = 2c+sp x n = np+4*hf (hf=0,1).
__global__ __launch_bounds__(256, 2)
void attn_kernel(const float* __restrict__ qg, const float* __restrict__ kg,
                 const float* __restrict__ vg, const float* __restrict__ ef,
                 const unsigned char* __restrict__ maskb,
                 const float* __restrict__ Wae, const float* __restrict__ bae,
                 float* __restrict__ acc) {
    const int t = threadIdx.x;
    const int lane = t & 63;
    const int wid = t >> 6;
    const int sp = lane >> 5;     // m parity
    const int np = (lane >> 3) & 3;
    const int h  = lane & 7;
    const int bx = blockIdx.x;
    const int n0  = (bx >> 3) * BN;
    const int grp = bx & 7;
    const int mb_w = grp * 128 + wid * 32;   // this wave's private 32 source rows

    __shared__ float smem[SMEM_F];
    float* wreg = smem + wid * WREG;         // wave-uniform base; b0=+0, b1=+PAR

    // --- per-thread constants (global, L2-hot) ---
    float qreg[2][DK];
    #pragma unroll
    for (int hf = 0; hf < 2; ++hf) {
        const float* qp = qg + (size_t)(n0 + np + 4 * hf) * DIM + h * DK;
        #pragma unroll
        for (int d4 = 0; d4 < 4; ++d4) {
            const float4 qv = *(const float4*)(qp + d4 * 4);
            qreg[hf][d4 * 4 + 0] = qv.x; qreg[hf][d4 * 4 + 1] = qv.y;
            qreg[hf][d4 * 4 + 2] = qv.z; qreg[hf][d4 * 4 + 3] = qv.w;
        }
    }
    float waec[EDIM];
    #pragma unroll
    for (int e = 0; e < EDIM; ++e) waec[e] = Wae[e * HEADS + h] * LOG2E;
    const float baeh = bae[h] * LOG2E;

    // mask bits for this wave's 32 m: u32 per hf; bit (2c+sp) via running >>2
    unsigned mk0 = *(const unsigned*)(maskb + (size_t)(n0 + np)     * 128 + (mb_w >> 3)) >> sp;
    unsigned mk1 = *(const unsigned*)(maskb + (size_t)(n0 + np + 4) * 128 + (mb_w >> 3)) >> sp;

    float sl[2] = {0.f, 0.f};
    float accv[2][DK], accT[2][EDIM];
    #pragma unroll
    for (int hf = 0; hf < 2; ++hf) {
        #pragma unroll
        for (int d = 0; d < DK; ++d) accv[hf][d] = 0.f;
        #pragma unroll
        for (int e = 0; e < EDIM; ++e) accT[hf][e] = 0.f;
    }

    // --- DMA per-lane source offsets (swizzled so linear LDS dst = swizzled layout) ---
    const int s0   = lane & 3;
    const int h0   = (lane >> 2) & 7;
    const int row0 = lane >> 5;                       // k/v: 2 rows per inst
    const int koffl = row0 * 128 + h0 * 16 + (((s0 - (h0 >> 1)) & 3) << 2);
    const int nn0 = lane >> 3;                        // ef: 8n x 2m x 16e, one inst
    const int mm0 = (lane >> 2) & 1;
    const int eoffl = nn0 * (NNODE * EDIM) + mm0 * EDIM + (((s0 - nn0) & 3) << 2);
    const float* efb = ef + (size_t)n0 * NNODE * EDIM;

    // --- read-side rotated sub-slot offsets (static-indexed, 4+4 regs) ---
    int krot[4], erot[4];
    const int rotk = (h >> 1) & 3;
    #pragma unroll
    for (int i = 0; i < 4; ++i) {
        krot[i] = ((i + rotk) & 3) << 2;
        erot[i] = ((i + np) & 3) << 2;
    }

#define ISSUE_BATCH(DB, MB)                                              \
    do {                                                                 \
        float* db = (DB);                                                \
        gll16(kg + (size_t)(MB) * DIM + koffl, db);                      \
        gll16(vg + (size_t)(MB) * DIM + koffl, db + 256);                \
        gll16(efb + (size_t)(MB) * EDIM + eoffl, db + 512);              \
    } while (0)

#define COMPUTE_CHUNK(DB)                                                      \
    do {                                                                       \
        const float* kl = (DB) + sp * 128 + h * 16;                            \
        const float* vl = kl + 256;                                            \
        const float* eb = (DB) + 512 + np * 32 + sp * 16;                      \
        float kk[DK], vv[DK];                                                  \
        _Pragma("unroll")                                                      \
        for (int i = 0; i < 4; ++i) {                                          \
            const float4 k4 = *(const float4*)(kl + krot[i]);                  \
            kk[i*4+0]=k4.x; kk[i*4+1]=k4.y; kk[i*4+2]=k4.z; kk[i*4+3]=k4.w;    \
            const float4 v4 = *(const float4*)(vl + krot[i]);                  \
            vv[i*4+0]=v4.x; vv[i*4+1]=v4.y; vv[i*4+2]=v4.z; vv[i*4+3]=v4.w;    \
        }                                                                      \
        _Pragma("unroll")                                                      \
        for (int hf = 0; hf < 2; ++hf) {                                       \
            float efv[EDIM];                                                   \
            _Pragma("unroll")                                                  \
            for (int i = 0; i < 4; ++i) {                                      \
                const float4 e4 = *(const float4*)(eb + hf * 128 + erot[i]);   \
                efv[i*4+0]=e4.x; efv[i*4+1]=e4.y;                              \
                efv[i*4+2]=e4.z; efv[i*4+3]=e4.w;                              \
            }                                                                  \
            float bias = baeh, dot = 0.f;                                      \
            _Pragma("unroll")                                                  \
            for (int e = 0; e < EDIM; ++e) bias = fmaf(efv[e], waec[e], bias); \
            _Pragma("unroll")                                                  \
            for (int d = 0; d < DK; ++d) dot = fmaf(qreg[hf][d], kk[d], dot);  \
            const float lg = fmaf(dot, 0.25f * LOG2E, bias);                   \
            const unsigned mv = (hf ? mk1 : mk0) & 1u;                         \
            const float p = mv ? __builtin_amdgcn_exp2f(lg) : 0.f;             \
            sl[hf] += p;                                                       \
            _Pragma("unroll")                                                  \
            for (int d = 0; d < DK; ++d) accv[hf][d] = fmaf(p, vv[d], accv[hf][d]); \
            _Pragma("unroll")                                                  \
            for (int e = 0; e < EDIM; ++e) accT[hf][e] = fmaf(p, efv[e], accT[hf][e]); \
        }                                                                      \
        mk0 >>= 2; mk1 >>= 2;                                                  \
    } while (0)

    // prologue: batch for chunk 0 (3 DMA outstanding + const loads above)
    ISSUE_BATCH(wreg, mb_w);

    // 2x-unrolled main loop over 16 chunks of 2 m-rows.
    // Ledger: first vmcnt(3) drains chunk-0 batch AND all prologue const loads
    // (FIFO-oldest, m135). Steady state: issue next batch (+3 -> 6), vmcnt(3)
    // drains current chunk's 3. Tail: vmcnt(0).
    #pragma unroll 1
    for (int cc = 0; cc < 16; cc += 2) {
        ISSUE_BATCH(wreg + PAR, mb_w + 2 * (cc + 1));
        asm volatile("s_waitcnt vmcnt(3)" ::: "memory");
        COMPUTE_CHUNK(wreg);
        if (cc < 14) {
            ISSUE_BATCH(wreg, mb_w + 2 * (cc + 2));
            asm volatile("s_waitcnt vmcnt(3)" ::: "memory");
        } else {
            asm volatile("s_waitcnt vmcnt(0)" ::: "memory");
        }
        COMPUTE_CHUNK(wreg + PAR);
    }
#undef ISSUE_BATCH
#undef COMPUTE_CHUNK

    // --- reduce sp-pairs within wave (lane ^ 32): combines the two m-parities ---
    #pragma unroll
    for (int hf = 0; hf < 2; ++hf) {
        sl[hf] += __shfl_xor(sl[hf], 32);
        #pragma unroll
        for (int d = 0; d < DK; ++d) accv[hf][d] += __shfl_xor(accv[hf][d], 32);
        #pragma unroll
        for (int e = 0; e < EDIM; ++e) accT[hf][e] += __shfl_xor(accT[hf][e], 32);
    }
    __syncthreads();                 // all waves done with private regions -> overlay
    float* red = smem;               // [w4][np4][h8][hf2][33] = 8448 f32 overlay
    if (lane < 32) {
        float* rp = &red[((wid * 4 + np) * 8 + h) * 66];
        #pragma unroll
        for (int hf = 0; hf < 2; ++hf) {
            rp[hf * 33 + 0] = sl[hf];
            #pragma unroll
            for (int d = 0; d < DK; ++d) rp[hf * 33 + 1 + d] = accv[hf][d];
            #pragma unroll
            for (int e = 0; e < EDIM; ++e) rp[hf * 33 + 17 + e] = accT[hf][e];
        }
    }
    __syncthreads();
    // --- combine 4 wave copies, plain store to this block's group slot ---
    for (int v = t; v < BN * HEADS * 33; v += 256) {   // 2112 values
        const int n = v / 264;
        const int rem = v - n * 264;
        const int hh = rem / 33;
        const int idx = rem - hh * 33;
        const int nnp = n & 3, hf = n >> 2;
        float sum = 0.f;
        #pragma unroll
        for (int w = 0; w < 4; ++w)
            sum += red[((w * 4 + nnp) * 8 + hh) * 66 + hf * 33 + idx];
        acc[((size_t)(n0 + n) * NGRP + grp) * 264 + rem] = sum;
    }
}

// ---------------- Kernel 3: epilogue (sum groups, Wve, normalize, Wo, residual) ----------------
__global__ __launch_bounds__(128)
void final_kernel(const float* __restrict__ acc,
                  const float* __restrict__ Wve, const float* __restrict__ bve,
                  const float* __restrict__ x,
                  const float* __restrict__ Wo, const float* __restrict__ bo,
                  float* __restrict__ out) {
    const int n = blockIdx.x, t = threadIdx.x;
    __shared__ float ab[HEADS * 33];
    __shared__ float orow[DIM];
    const float* ap = acc + (size_t)n * NGRP * 264;
    for (int u = t; u < HEADS * 33; u += 128) {
        float sv = 0.f;
        #pragma unroll
        for (int g = 0; g < NGRP; ++g) sv += ap[g * 264 + u];
        ab[u] = sv;
    }
    __syncthreads();
    const int col = t, hh = col >> 4, dd = col & 15;
    const float slv = ab[hh * 33];
    float acc2 = 0.f;
    #pragma unroll
    for (int e = 0; e < EDIM; ++e) acc2 = fmaf(ab[hh * 33 + 17 + e], Wve[e * DIM + col], acc2);
    orow[col] = (ab[hh * 33 + 1 + dd] + acc2) / slv + bve[col];
    __syncthreads();
    float o0 = bo[col] + x[(size_t)n * DIM + col], o1 = 0.f;
    #pragma unroll 8
    for (int i = 0; i < DIM; i += 2) {
        o0 = fmaf(orow[i],     Wo[i * DIM + col],       o0);
        o1 = fmaf(orow[i + 1], Wo[(i + 1) * DIM + col], o1);
    }
    out[(size_t)n * DIM + col] = o0 + o1;
}

extern "C" void kernel_launch(void* const* d_in, const int* in_sizes, int n_in,
                              void* d_out, int out_size, void* d_ws, size_t ws_size,
                              hipStream_t stream) {
    const float* x     = (const float*)d_in[0];
    const float* ef    = (const float*)d_in[1];
    const int*   mask  = (const int*)d_in[2];
    const float* Wq    = (const float*)d_in[3];
    const float* bq    = (const float*)d_in[4];
    const float* Wk    = (const float*)d_in[5];
    const float* bk    = (const float*)d_in[6];
    const float* Wv    = (const float*)d_in[7];
    const float* bv    = (const float*)d_in[8];
    const float* Wae   = (const float*)d_in[9];
    const float* bae   = (const float*)d_in[10];
    const float* Wve   = (const float*)d_in[11];
    const float* bve   = (const float*)d_in[12];
    const float* Wo    = (const float*)d_in[13];
    const float* bo    = (const float*)d_in[14];
    const float* gamma = (const float*)d_in[15];
    const float* beta  = (const float*)d_in[16];

    float* ws = (float*)d_ws;
    float* accb = ws;                                   // 1024*8*264 f32
    float* qg   = ws + (size_t)NNODE * NGRP * 264;
    float* kg   = qg + (size_t)NNODE * DIM;
    float* vg   = kg + (size_t)NNODE * DIM;
    unsigned char* maskb = (unsigned char*)(vg + (size_t)NNODE * DIM);  // 128 KB

    ln_qkv_kernel<<<NNODE, 384, 0, stream>>>(x, Wq, bq, Wk, bk, Wv, bv, gamma, beta,
                                             mask, qg, kg, vg, maskb);
    attn_kernel<<<(NNODE / BN) * NGRP, 256, 0, stream>>>(qg, kg, vg, ef, maskb, Wae, bae, accb);
    final_kernel<<<NNODE, 128, 0, stream>>>(accb, Wve, bve, x, Wo, bo, (float*)d_out);
}